// Round 2
// baseline (905.898 us; speedup 1.0000x reference)
//
#include <hip/hip_runtime.h>
#include <math.h>

// DeepMatching loss, MI355X. Pipeline per direction:
//   corr = d1^T d2  (per-batch GEMM, K=128)  -> 4 pyramid levels -> final loss.
// corr is chunked by hp-row pairs to fit unknown ws_size (max ~53MB needed).

#define C_EPS 0.03f
#define INV2P09 0.5358867312681466f   // 2^-0.9
#define INV4P09 0.2871745887492587f   // 4^-0.9

// ---------------- gather d1 sub-grid: a[b*128+d][u][v] = desc[b][d][20+8u][20+8v]
__global__ __launch_bounds__(256) void gather_a_k(
    const float* __restrict__ desc, float* __restrict__ a)
{
    const int TOT = 4 * 128 * 28 * 28;
    int idx = blockIdx.x * 256 + threadIdx.x;
    if (idx >= TOT) return;
    int v  = idx % 28;
    int t  = idx / 28;
    int u  = t % 28;
    int bd = t / 28;
    a[idx] = desc[(size_t)bd * 65536 + (size_t)(20 + 8 * u) * 256 + (20 + 8 * v)];
}

// ---------------- correlation GEMM (one batch, one hp-row chunk)
// A: [128][784] (gathered d1, batch offset applied), column range [p0+m0, +112)
// descB: desc + b*128*65536 ; B[k][q] = descB[k*65536 + (16+2*qy)*256 + (16+2*qx)]
// C: chunk [rcur*56][12544], row m local (global p = p0 + m)
__global__ __launch_bounds__(256) void gemm_corr(
    const float* __restrict__ A, const float* __restrict__ descB,
    float* __restrict__ C, int p0)
{
    __shared__ float As[16][112];
    __shared__ float Bs[16][128];
    const int tid = threadIdx.x;
    const int tx = tid & 15;   // 16 col-groups, 8 cols each (split 4+4)
    const int ty = tid >> 4;   // 16 row-groups, 7 rows each
    const int n0 = blockIdx.x * 128;
    const int m0 = blockIdx.y * 112;

    // hoisted staging coordinates (loop-invariant)
    int arow[7], acol[7];
#pragma unroll
    for (int i = 0; i < 7; ++i) {
        int idx = tid + i * 256;          // 0..1791
        arow[i] = idx / 112;
        acol[i] = idx - arow[i] * 112;
    }
    int brow[8], bcol[8]; size_t bofs[8];
#pragma unroll
    for (int i = 0; i < 8; ++i) {
        int idx = tid + i * 256;          // 0..2047
        int r = idx >> 7, c = idx & 127;
        int q = n0 + c;
        int qy = q / 112;
        int qx = q - qy * 112;
        brow[i] = r; bcol[i] = c;
        bofs[i] = (size_t)(16 + 2 * qy) * 256 + (16 + 2 * qx);
    }
    const float* Abase = A + (size_t)(p0 + m0);

    float acc[7][8];
#pragma unroll
    for (int i = 0; i < 7; ++i)
#pragma unroll
        for (int j = 0; j < 8; ++j) acc[i][j] = 0.f;

    for (int k0 = 0; k0 < 128; k0 += 16) {
#pragma unroll
        for (int i = 0; i < 7; ++i)
            As[arow[i]][acol[i]] = Abase[(size_t)(k0 + arow[i]) * 784 + acol[i]];
#pragma unroll
        for (int i = 0; i < 8; ++i)
            Bs[brow[i]][bcol[i]] = descB[(size_t)(k0 + brow[i]) * 65536 + bofs[i]];
        __syncthreads();
#pragma unroll
        for (int k = 0; k < 16; ++k) {
            float av[7], bv[8];
#pragma unroll
            for (int i = 0; i < 7; ++i) av[i] = As[k][ty * 7 + i];
            *(float4*)&bv[0] = *(float4*)&Bs[k][tx * 4];        // cols tx*4..+3
            *(float4*)&bv[4] = *(float4*)&Bs[k][64 + tx * 4];   // cols 64+tx*4..+3
#pragma unroll
            for (int i = 0; i < 7; ++i)
#pragma unroll
                for (int j = 0; j < 8; ++j)
                    acc[i][j] = fmaf(av[i], bv[j], acc[i][j]);
        }
        __syncthreads();
    }
#pragma unroll
    for (int i = 0; i < 7; ++i) {
        size_t base = (size_t)(m0 + ty * 7 + i) * 12544 + n0;
        float4 v0 = make_float4(acc[i][0], acc[i][1], acc[i][2], acc[i][3]);
        float4 v1 = make_float4(acc[i][4], acc[i][5], acc[i][6], acc[i][7]);
        *(float4*)&C[base + tx * 4] = v0;
        *(float4*)&C[base + 64 + tx * 4] = v1;
    }
}

// ---------------- maxpool3s2(pad1) + relu^1.5 at one pooled position
__device__ __forceinline__ float pool_rect(const float* __restrict__ m,
                                           int py, int px, int H2, int W2)
{
    int r0 = max(2 * py - 1, 0), r1 = min(2 * py + 1, H2 - 1);
    int c0 = max(2 * px - 1, 0), c1 = min(2 * px + 1, W2 - 1);
    float mx = -1e30f;
    for (int r = r0; r <= r1; ++r)
        for (int c = c0; c <= c1; ++c)
            mx = fmaxf(mx, m[r * W2 + c]);
    mx = fmaxf(mx, 0.f);
    return mx * sqrtf(mx);
}

// ---------------- level 0 (chunked): in [rcur*56][12544] local rows -> out lvl0 (per-b base)
__global__ __launch_bounds__(256) void level0_chunk(
    const float* __restrict__ in, float* __restrict__ out, int hp0, int rcur)
{
    int total = rcur * 14 * 56 * 56;
    int idx = blockIdx.x * 256 + threadIdx.x;
    if (idx >= total) return;
    int j = idx % 56; int t = idx / 56;
    int i = t % 56;   t /= 56;
    int wp = t % 14;  int hpl = t / 14;

    float res = 0.f;
#pragma unroll
    for (int dy = 0; dy < 2; ++dy)
#pragma unroll
        for (int dx = 0; dx < 2; ++dx) {
            int py = i + 2 * dy - 1, px = j + 2 * dx - 1;
            if (py < 0 || py >= 56 || px < 0 || px >= 56) continue;
            const float* m = in + (size_t)((2 * hpl + dy) * 28 + (2 * wp + dx)) * 12544;
            res += pool_rect(m, py, px, 112, 112);
        }
    int cnt = ((i == 0 || i == 55) ? 1 : 2) * ((j == 0 || j == 55) ? 1 : 2);
    float inv = (cnt == 1) ? 1.f : (cnt == 2) ? INV2P09 : INV4P09;
    out[(size_t)((hp0 + hpl) * 14 + wp) * 3136 + i * 56 + j] = res * inv;
}

// ---------------- generic pyramid level: (B,H1,W1,H2,W2) -> (B,H1/2,W1/2,H2/2,W2/2)
__global__ __launch_bounds__(256) void level_generic(
    const float* __restrict__ in, float* __restrict__ out,
    int B, int H1, int W1, int H2, int W2)
{
    int Hp = H1 >> 1, Wp = W1 >> 1, H2p = H2 >> 1, W2p = W2 >> 1;
    int total = B * Hp * Wp * H2p * W2p;
    int idx = blockIdx.x * 256 + threadIdx.x;
    if (idx >= total) return;
    int j = idx % W2p; int t = idx / W2p;
    int i = t % H2p;   t /= H2p;
    int wp = t % Wp;   t /= Wp;
    int hp = t % Hp;   int b = t / Hp;

    float res = 0.f;
#pragma unroll
    for (int dy = 0; dy < 2; ++dy)
#pragma unroll
        for (int dx = 0; dx < 2; ++dx) {
            int py = i + 2 * dy - 1, px = j + 2 * dx - 1;
            if (py < 0 || py >= H2p || px < 0 || px >= W2p) continue;
            const float* m = in +
                (size_t)((b * H1 + 2 * hp + dy) * W1 + (2 * wp + dx)) * H2 * W2;
            res += pool_rect(m, py, px, H2, W2);
        }
    int cnt = ((i == 0 || i == H2p - 1) ? 1 : 2) * ((j == 0 || j == W2p - 1) ? 1 : 2);
    float inv = (cnt == 1) ? 1.f : (cnt == 2) ? INV2P09 : INV4P09;
    out[idx] = res * inv;
}

// ---------------- final: rectify, per-(dir,b) denom, -sum((r/denom)^2)/8
__global__ void finalize_k(const float* __restrict__ l3, float* __restrict__ out)
{
    __shared__ float accv[8];
    int t = threadIdx.x;
    if (t < 8) {
        const float* p = l3 + t * 49;   // [dir][b][49]
        float sum = 0.f;
        for (int i = 0; i < 49; ++i) {
            float v = fmaxf(p[i], 0.f);
            sum += v * sqrtf(v);
        }
        float inv = 1.f / (sum + C_EPS);
        float q = 0.f;
        for (int i = 0; i < 49; ++i) {
            float v = fmaxf(p[i], 0.f);
            float r = v * sqrtf(v) * inv;
            q += r * r;
        }
        accv[t] = q;
    }
    __syncthreads();
    if (t == 0) {
        float s = 0.f;
        for (int i = 0; i < 8; ++i) s += accv[i];
        // loss_dir = -sum_b(q)/4 ; out = (loss_f + loss_b)/2 = -(sum all)/8
        out[0] = -s * 0.125f;
    }
}

extern "C" void kernel_launch(void* const* d_in, const int* in_sizes, int n_in,
                              void* d_out, int out_size, void* d_ws, size_t ws_size,
                              hipStream_t stream)
{
    const float* desc1 = (const float*)d_in[0];
    const float* desc2 = (const float*)d_in[1];
    float* out = (float*)d_out;
    float* ws = (float*)d_ws;

    const size_t NA  = 4ull * 128 * 28 * 28;       // 401,408
    const size_t NL0 = 4ull * 14 * 14 * 56 * 56;   // 2,458,624
    const size_t NL1 = 4ull * 7 * 7 * 28 * 28;     // 153,664
    const size_t NL2 = 4ull * 3 * 3 * 14 * 14;     // 7,056
    const size_t NL3 = 2ull * 4 * 49;              // 392 (both directions)

    float* a1   = ws;
    float* a2   = a1 + NA;
    float* l0   = a2 + NA;
    float* l1   = l0 + NL0;
    float* l2   = l1 + NL1;
    float* l3   = l2 + NL2;
    float* corr = l3 + NL3;

    size_t fixedf = (size_t)(corr - ws);
    long long availf = (long long)(ws_size / 4) - (long long)fixedf;
    const long long perHp = 2ll * 28 * 12544;      // floats per hp-row of corr
    int RC = (int)(availf / perHp);
    if (RC > 14) RC = 14;
    RC &= ~1;                                      // keep even (BM=112 = 2 h1-rows)
    if (RC < 2) RC = 2;                            // below this ws is unusable anyway

    const int NAtot = (int)NA;
    gather_a_k<<<(NAtot + 255) / 256, 256, 0, stream>>>(desc1, a1);
    gather_a_k<<<(NAtot + 255) / 256, 256, 0, stream>>>(desc2, a2);

    for (int dir = 0; dir < 2; ++dir) {
        const float* A     = dir ? a2 : a1;
        const float* descB = dir ? desc1 : desc2;
        for (int b = 0; b < 4; ++b) {
            const float* Ab = A + (size_t)b * 128 * 784;
            const float* Bb = descB + (size_t)b * 128 * 65536;
            float* l0b = l0 + (size_t)b * 14 * 14 * 56 * 56;
            for (int hp0 = 0; hp0 < 14; hp0 += RC) {
                int rcur = (RC < 14 - hp0) ? RC : (14 - hp0);
                int p0 = hp0 * 56;
                dim3 ggrid(98, rcur / 2);
                gemm_corr<<<ggrid, 256, 0, stream>>>(Ab, Bb, corr, p0);
                int tot = rcur * 14 * 56 * 56;
                level0_chunk<<<(tot + 255) / 256, 256, 0, stream>>>(corr, l0b, hp0, rcur);
            }
        }
        level_generic<<<((int)NL1 + 255) / 256, 256, 0, stream>>>(l0, l1, 4, 14, 14, 56, 56);
        level_generic<<<((int)NL2 + 255) / 256, 256, 0, stream>>>(l1, l2, 4, 7, 7, 28, 28);
        level_generic<<<(196 + 255) / 256, 256, 0, stream>>>(l2, l3 + dir * 196, 4, 3, 3, 14, 14);
    }
    finalize_k<<<1, 64, 0, stream>>>(l3, out);
}

// Round 3
// 522.895 us; speedup vs baseline: 1.7325x; 1.7325x over previous
//
#include <hip/hip_runtime.h>
#include <math.h>

// DeepMatching loss, MI355X (gfx950).
// Pipeline: pack desc -> f16 q-major B matrices; per direction:
//   corr(f16) = MFMA GEMM -> separable maxpool+rect -> shift-add aggregate
//   -> 3 generic pyramid levels -> finalize.

typedef _Float16 f16x8 __attribute__((ext_vector_type(8)));
typedef float    f32x4 __attribute__((ext_vector_type(4)));

#define C_EPS 0.03f
#define INV2P09 0.5358867312681466f   // 2^-0.9
#define INV4P09 0.2871745887492587f   // 4^-0.9

// ---------------- pack: Bp[b][q][k] = (f16) desc[b][k][16+2qy][16+2qx], q=qy*112+qx
__global__ __launch_bounds__(256) void pack_b_k(
    const float* __restrict__ desc, _Float16* __restrict__ Bp)
{
    int idx = blockIdx.x * 256 + threadIdx.x;   // (b,q,k8): 4*12544*16 threads
    if (idx >= 4 * 12544 * 16) return;
    int k8 = idx & 15;
    int t  = idx >> 4;
    int q  = t % 12544;
    int b  = t / 12544;
    int qy = q / 112, qx = q - qy * 112;
    const float* src = desc +
        (((size_t)(b * 128 + k8 * 8) * 256 + (16 + 2 * qy)) * 256 + (16 + 2 * qx));
    f16x8 v;
#pragma unroll
    for (int j = 0; j < 8; ++j) v[j] = (_Float16)src[(size_t)j * 65536];
    *(f16x8*)(Bp + (size_t)idx * 8) = v;    // == (b*12544+q)*128 + k8*8
}

// ---------------- MFMA GEMM: corr[b][p][q] = sum_k A[p][k]*B[q][k]
// A rows are a sparse subset of BpA rows: p=(u,v) -> q_A = 226+448u+4v.
// Block tile 128x128, 4 waves (2x2), wave tile 64x64 = 4x4 mfma 16x16x32.
__global__ __launch_bounds__(256) void gemm_mfma(
    const _Float16* __restrict__ BpA, const _Float16* __restrict__ BpB,
    _Float16* __restrict__ C)           // [4][896][12544] f16 (rows>=784 are zeros)
{
    const int n0 = blockIdx.x * 128;
    const int m0 = blockIdx.y * 128;
    const int b  = blockIdx.z;
    const int tid  = threadIdx.x;
    const int lane = tid & 63;
    const int w  = tid >> 6;
    const int wr = w >> 1, wc = w & 1;
    const int l15 = lane & 15, lk = lane >> 4;

    const _Float16* BA = BpA + (size_t)b * 12544 * 128;
    const _Float16* BB = BpB + (size_t)b * 12544 * 128;

    int aoff[4]; bool avalid[4];
#pragma unroll
    for (int m = 0; m < 4; ++m) {
        int pb = m0 + wr * 64 + m * 16;       // subtile base (wave-uniform)
        avalid[m] = pb < 784;
        int p = pb + l15; if (p > 783) p = 783;   // clamp => address always in-bounds
        int u = p / 28, v = p - u * 28;
        aoff[m] = (226 + 448 * u + 4 * v) * 128;
    }
    int boff[4];
#pragma unroll
    for (int n = 0; n < 4; ++n)
        boff[n] = (n0 + wc * 64 + n * 16 + l15) * 128;

    f32x4 acc[4][4];
#pragma unroll
    for (int m = 0; m < 4; ++m)
#pragma unroll
        for (int n = 0; n < 4; ++n) acc[m][n] = (f32x4){0.f, 0.f, 0.f, 0.f};

    const f16x8 az = {};
#pragma unroll
    for (int k8 = 0; k8 < 4; ++k8) {
        const int ko = k8 * 32 + lk * 8;
        f16x8 af[4], bf[4];
#pragma unroll
        for (int m = 0; m < 4; ++m)
            af[m] = avalid[m] ? *(const f16x8*)(BA + aoff[m] + ko) : az;
#pragma unroll
        for (int n = 0; n < 4; ++n)
            bf[n] = *(const f16x8*)(BB + boff[n] + ko);
#pragma unroll
        for (int m = 0; m < 4; ++m)
#pragma unroll
            for (int n = 0; n < 4; ++n)
                acc[m][n] = __builtin_amdgcn_mfma_f32_16x16x32_f16(
                    af[m], bf[n], acc[m][n], 0, 0, 0);
    }

    _Float16* Cb = C + (size_t)b * 896 * 12544;
#pragma unroll
    for (int m = 0; m < 4; ++m) {
        int rbase = m0 + wr * 64 + m * 16 + lk * 4;
#pragma unroll
        for (int n = 0; n < 4; ++n) {
            int col = n0 + wc * 64 + n * 16 + l15;
#pragma unroll
            for (int r = 0; r < 4; ++r)
                Cb[(size_t)(rbase + r) * 12544 + col] = (_Float16)acc[m][n][r];
        }
    }
}

// ---------------- separable maxpool3s2(pad1) + relu^1.5 per corr row
// corr f16 [4][896][12544] -> PR f32 [4][784][3136]; one block per (b,p)
__global__ __launch_bounds__(256) void pool_rect_k(
    const _Float16* __restrict__ corr, float* __restrict__ PR)
{
    __shared__ float tmp[112 * 56];
    int blk = blockIdx.x;               // b*784 + p
    int b = blk / 784, p = blk - b * 784;
    const _Float16* row = corr + ((size_t)b * 896 + p) * 12544;
    int tid = threadIdx.x;
    for (int idx = tid; idx < 112 * 56; idx += 256) {
        int r = idx / 56, pc = idx - (idx / 56) * 56;
        int c = 2 * pc;
        float v1 = (float)row[r * 112 + c];
        float v2 = (float)row[r * 112 + c + 1];          // c+1 <= 111 always
        float v = fmaxf(v1, v2);
        if (pc > 0) v = fmaxf(v, (float)row[r * 112 + c - 1]);
        tmp[idx] = v;
    }
    __syncthreads();
    float* outp = PR + ((size_t)b * 784 + p) * 3136;
    for (int idx = tid; idx < 3136; idx += 256) {
        int pr = idx / 56, pc = idx - (idx / 56) * 56;
        float v = fmaxf(tmp[2 * pr * 56 + pc], tmp[(2 * pr + 1) * 56 + pc]);
        if (pr > 0) v = fmaxf(v, tmp[(2 * pr - 1) * 56 + pc]);
        v = fmaxf(v, 0.f);
        outp[idx] = v * sqrtf(v);
    }
}

// ---------------- shift-add aggregate: PR [4][784][3136] -> l0 [4][196][3136]
__global__ __launch_bounds__(256) void aggregate_k(
    const float* __restrict__ PR, float* __restrict__ l0)
{
    int idx = blockIdx.x * 256 + threadIdx.x;   // b,hp,wp,i,j
    if (idx >= 4 * 196 * 3136) return;
    int j = idx % 56; int t = idx / 56;
    int i = t % 56;   t /= 56;
    int wp = t % 14;  t /= 14;
    int hp = t % 14;  int b = t / 14;
    float res = 0.f;
#pragma unroll
    for (int dy = 0; dy < 2; ++dy) {
        int ii = i + 2 * dy - 1;
        if (ii < 0 || ii >= 56) continue;
#pragma unroll
        for (int dx = 0; dx < 2; ++dx) {
            int jj = j + 2 * dx - 1;
            if (jj < 0 || jj >= 56) continue;
            int pc = (2 * hp + dy) * 28 + (2 * wp + dx);
            res += PR[((size_t)b * 784 + pc) * 3136 + ii * 56 + jj];
        }
    }
    int cnt = ((i == 0 || i == 55) ? 1 : 2) * ((j == 0 || j == 55) ? 1 : 2);
    float inv = (cnt == 1) ? 1.f : (cnt == 2) ? INV2P09 : INV4P09;
    l0[idx] = res * inv;
}

// ---------------- generic pyramid level (unchanged, f32)
__device__ __forceinline__ float pool_rect(const float* __restrict__ m,
                                           int py, int px, int H2, int W2)
{
    int r0 = max(2 * py - 1, 0), r1 = min(2 * py + 1, H2 - 1);
    int c0 = max(2 * px - 1, 0), c1 = min(2 * px + 1, W2 - 1);
    float mx = -1e30f;
    for (int r = r0; r <= r1; ++r)
        for (int c = c0; c <= c1; ++c)
            mx = fmaxf(mx, m[r * W2 + c]);
    mx = fmaxf(mx, 0.f);
    return mx * sqrtf(mx);
}

__global__ __launch_bounds__(256) void level_generic(
    const float* __restrict__ in, float* __restrict__ out,
    int B, int H1, int W1, int H2, int W2)
{
    int Hp = H1 >> 1, Wp = W1 >> 1, H2p = H2 >> 1, W2p = W2 >> 1;
    int total = B * Hp * Wp * H2p * W2p;
    int idx = blockIdx.x * 256 + threadIdx.x;
    if (idx >= total) return;
    int j = idx % W2p; int t = idx / W2p;
    int i = t % H2p;   t /= H2p;
    int wp = t % Wp;   t /= Wp;
    int hp = t % Hp;   int b = t / Hp;

    float res = 0.f;
#pragma unroll
    for (int dy = 0; dy < 2; ++dy)
#pragma unroll
        for (int dx = 0; dx < 2; ++dx) {
            int py = i + 2 * dy - 1, px = j + 2 * dx - 1;
            if (py < 0 || py >= H2p || px < 0 || px >= W2p) continue;
            const float* m = in +
                (size_t)((b * H1 + 2 * hp + dy) * W1 + (2 * wp + dx)) * H2 * W2;
            res += pool_rect(m, py, px, H2, W2);
        }
    int cnt = ((i == 0 || i == H2p - 1) ? 1 : 2) * ((j == 0 || j == W2p - 1) ? 1 : 2);
    float inv = (cnt == 1) ? 1.f : (cnt == 2) ? INV2P09 : INV4P09;
    out[idx] = res * inv;
}

// ---------------- final: rectify, per-(dir,b) denom, -sum((r/denom)^2)/8
__global__ void finalize_k(const float* __restrict__ l3, float* __restrict__ out)
{
    __shared__ float accv[8];
    int t = threadIdx.x;
    if (t < 8) {
        const float* p = l3 + t * 49;   // [dir][b][49]
        float sum = 0.f;
        for (int i = 0; i < 49; ++i) {
            float v = fmaxf(p[i], 0.f);
            sum += v * sqrtf(v);
        }
        float inv = 1.f / (sum + C_EPS);
        float q = 0.f;
        for (int i = 0; i < 49; ++i) {
            float v = fmaxf(p[i], 0.f);
            float r = v * sqrtf(v) * inv;
            q += r * r;
        }
        accv[t] = q;
    }
    __syncthreads();
    if (t == 0) {
        float s = 0.f;
        for (int i = 0; i < 8; ++i) s += accv[i];
        out[0] = -s * 0.125f;   // ((-q0/4)+(-q1/4))/2
    }
}

extern "C" void kernel_launch(void* const* d_in, const int* in_sizes, int n_in,
                              void* d_out, int out_size, void* d_ws, size_t ws_size,
                              hipStream_t stream)
{
    const float* desc1 = (const float*)d_in[0];
    const float* desc2 = (const float*)d_in[1];
    float* out = (float*)d_out;

    // ws layout
    _Float16* Bp1  = (_Float16*)d_ws;                    // 4*12544*128 halves
    _Float16* Bp2  = Bp1 + 4ull * 12544 * 128;
    _Float16* corr = Bp2 + 4ull * 12544 * 128;           // 4*896*12544 halves
    float*    PR   = (float*)(corr + 4ull * 896 * 12544);// 4*784*3136 f32
    float*    l0   = PR + 4ull * 784 * 3136;
    float*    l1   = l0 + 4ull * 196 * 3136;
    float*    l2   = l1 + 4ull * 49 * 784;
    float*    l3   = l2 + 4ull * 9 * 196;
    // total ~165 MB (< 512 MB ws observed)

    const int PACK_TOT = 4 * 12544 * 16;
    pack_b_k<<<(PACK_TOT + 255) / 256, 256, 0, stream>>>(desc1, Bp1);
    pack_b_k<<<(PACK_TOT + 255) / 256, 256, 0, stream>>>(desc2, Bp2);

    for (int dir = 0; dir < 2; ++dir) {
        const _Float16* BA = dir ? Bp2 : Bp1;
        const _Float16* BB = dir ? Bp1 : Bp2;
        gemm_mfma<<<dim3(98, 7, 4), 256, 0, stream>>>(BA, BB, corr);
        pool_rect_k<<<4 * 784, 256, 0, stream>>>(corr, PR);
        const int AGG_TOT = 4 * 196 * 3136;
        aggregate_k<<<(AGG_TOT + 255) / 256, 256, 0, stream>>>(PR, l0);
        level_generic<<<(4 * 49 * 784 + 255) / 256, 256, 0, stream>>>(l0, l1, 4, 14, 14, 56, 56);
        level_generic<<<(4 * 9 * 196 + 255) / 256, 256, 0, stream>>>(l1, l2, 4, 7, 7, 28, 28);
        level_generic<<<1, 256, 0, stream>>>(l2, l3 + dir * 196, 4, 3, 3, 14, 14);
    }
    finalize_k<<<1, 64, 0, stream>>>(l3, out);
}